// Round 6
// baseline (149.764 us; speedup 1.0000x reference)
//
#include <hip/hip_runtime.h>
#include <hip/hip_bf16.h>

// Problem constants
#define D       512       // embedding dim (= C)
#define K       2048      // codebook size
#define HW      1024      // 32*32
#define N_TOK   16384     // 16*HW
#define NUMEL   8388608   // 16*512*32*32

typedef __attribute__((ext_vector_type(8))) short  short8;   // 8 bf16 = 4 VGPRs
typedef __attribute__((ext_vector_type(4))) float  floatx4;

// async global->LDS DMA, 16 B per lane; LDS dest is wave-uniform base + lane*16
#define GLD_LDS16(gptr, lptr) \
    __builtin_amdgcn_global_load_lds((const __attribute__((address_space(1))) void*)(gptr), \
                                     (__attribute__((address_space(3))) void*)(lptr), 16, 0, 0)

// ---- ws layout (bytes) ----
// zb is now TILED: [b][cg][1024 tok][64 ch] bf16 (16*8*1024*64*2 = 16777216 B, same size).
#define WS_ZB    0           // bf16 tiled z (see above)
#define WS_EB    16777216    // bf16 [2048][512]
#define WS_ESQ   18874368    // f32  [2048]
#define WS_MINB  18882560    // u32  [16384] packed (21-bit dist key | 11-bit idx); init in kp
#define WS_PZ    18948096    // f32  [512]  per-kp-block sum z^2 partials (plain writes)
#define WS_PARTS 18956288    // f32  [256]  per-image decoded-key partials (16 used)
#define WS_CNT2  18957312    // u32  [1]    completion counter (zeroed by kp)

// monotone fp32 -> sortable u32, and its inverse
__device__ __forceinline__ unsigned int fkey(float f) {
    unsigned int b = __float_as_uint(f);
    return b ^ ((unsigned int)((int)b >> 31) | 0x80000000u);
}
__device__ __forceinline__ float unfkey(unsigned int u) {
    unsigned int b = (u & 0x80000000u) ? (u ^ 0x80000000u) : ~u;
    return __uint_as_float(b);
}

// ---------------- Kernel P2: prep with CONTIGUOUS reads and writes ----------------
// blocks [0,512): z transpose. block = (image b, 64-ch group cg, 256-token pass p).
//   Reads z[b, cg*64..+64, p*256..+256]: 64 chunks x 1 KB contiguous (vs 256 B before).
//   LDS f32 tile t[64][257] w/ per-granule column rotation -> 2-way bank alias both phases.
//   Writes zb tile [256 tok][64 ch] bf16 = ONE contiguous 32 KB region.
// blocks [512,768): emb rows -> eb bf16 + esq. 8 rows/block, half-wave per row, no LDS.
__global__ __launch_bounds__(256) void kp(const float* __restrict__ z,
                                          const float* __restrict__ emb,
                                          __hip_bfloat16* __restrict__ zb,
                                          __hip_bfloat16* __restrict__ eb,
                                          float* __restrict__ esq,
                                          float* __restrict__ pz,
                                          unsigned int* __restrict__ minb,
                                          unsigned int* __restrict__ cnt2) {
    __shared__ float t[64][257];     // 65.8 KB -> 2 blocks/CU
    __shared__ float ls[4];
    int blk = blockIdx.x;
    int tid = threadIdx.x;
    if (blk < 512) {
        if (tid < 32) minb[blk * 32 + tid] = 0xFFFFFFFFu;
        if (blk == 0 && tid == 32) *cnt2 = 0u;
        int b  = blk >> 5;           // image 0..15
        int cg = (blk >> 2) & 7;     // 64-ch group 0..7
        int p  = blk & 3;            // 256-token pass 0..3
        const float* zp = z + ((size_t)(b * 512 + cg * 64)) * HW + p * 256;
        float s = 0.f;
        // read: e = r(64 ch) x c4(64 float4s of 256 tok); per wave = 1 KB contiguous
#pragma unroll
        for (int i = 0; i < 16; ++i) {
            int e = tid + 256 * i;
            int r = e >> 6, c4 = e & 63;
            float4 v = *(const float4*)(zp + (size_t)r * HW + c4 * 4);
            s += v.x * v.x + v.y * v.y + v.z * v.z + v.w * v.w;
            int rot = (c4 >> 3) & 3;  // rotate elems within the 16B granule: kills column conflicts
            t[r][c4 * 4 + ((0 + rot) & 3)] = v.x;
            t[r][c4 * 4 + ((1 + rot) & 3)] = v.y;
            t[r][c4 * 4 + ((2 + rot) & 3)] = v.z;
            t[r][c4 * 4 + ((3 + rot) & 3)] = v.w;
        }
#pragma unroll
        for (int o = 32; o; o >>= 1) s += __shfl_down(s, o);
        if ((tid & 63) == 0) ls[tid >> 6] = s;
        __syncthreads();
        if (tid == 0) pz[blk] = ls[0] + ls[1] + ls[2] + ls[3];
        // write: one contiguous 32 KB tile zb[b][cg][p*256 + tt][ch]
        __hip_bfloat16* op = zb + ((size_t)((b * 8 + cg) * 1024 + p * 256)) * 64;
#pragma unroll
        for (int i = 0; i < 16; ++i) {
            int e = tid + 256 * i;
            int tt = e >> 4, cq = e & 15;      // token 0..255, ch-quad 0..15
            int col = (tt & ~3) + ((tt + (tt >> 5)) & 3);   // inverse of the write rotation
            __hip_bfloat16 q0 = __float2bfloat16(t[cq * 4 + 0][col]);
            __hip_bfloat16 q1 = __float2bfloat16(t[cq * 4 + 1][col]);
            __hip_bfloat16 q2 = __float2bfloat16(t[cq * 4 + 2][col]);
            __hip_bfloat16 q3 = __float2bfloat16(t[cq * 4 + 3][col]);
            ushort4 u;
            u.x = *(unsigned short*)&q0; u.y = *(unsigned short*)&q1;
            u.z = *(unsigned short*)&q2; u.w = *(unsigned short*)&q3;
            *(ushort4*)(op + (size_t)tt * 64 + cq * 4) = u;
        }
    } else {
        // emb prep: 8 rows per block, one 32-lane half-wave per row; coalesced 512 B stores
        int k0 = (blk - 512) * 8;
        int h = tid >> 5, l = tid & 31;
        int row = k0 + h;
        const float* ep = emb + (size_t)row * D;
        __hip_bfloat16* op = eb + (size_t)row * D;
        float s = 0.f;
#pragma unroll
        for (int j = 0; j < 4; ++j) {
            float4 v = *(const float4*)(ep + l * 4 + j * 128);
            s += v.x * v.x + v.y * v.y + v.z * v.z + v.w * v.w;
            __hip_bfloat16 q0 = __float2bfloat16(v.x);
            __hip_bfloat16 q1 = __float2bfloat16(v.y);
            __hip_bfloat16 q2 = __float2bfloat16(v.z);
            __hip_bfloat16 q3 = __float2bfloat16(v.w);
            ushort4 u;
            u.x = *(unsigned short*)&q0; u.y = *(unsigned short*)&q1;
            u.z = *(unsigned short*)&q2; u.w = *(unsigned short*)&q3;
            *(ushort4*)(op + l * 4 + j * 128) = u;
        }
#pragma unroll
        for (int o = 16; o; o >>= 1) s += __shfl_down(s, o, 32);
        if (l == 0) esq[row] = s;
    }
}

// ---------------- Kernel G4: 256x256 tile, 8-wave, BK=64 dbuf (A-base updated for tiled zb) ----------------
__global__ __launch_bounds__(512, 2) void kg(const __hip_bfloat16* __restrict__ zb,
                                             const __hip_bfloat16* __restrict__ eb,
                                             const float* __restrict__ esq,
                                             unsigned int* __restrict__ minb) {
    __shared__ __hip_bfloat16 As[2][256 * 64];   // 32 KiB per slot
    __shared__ __hip_bfloat16 Bs[2][256 * 64];   // total 128 KiB

    int bid   = blockIdx.x;
    int swzb  = (bid & 7) * 64 + (bid >> 3);
    int mtile = swzb >> 3;            // 0..63
    int ntile = swzb & 7;             // 0..7

    int tid  = threadIdx.x;
    int wv   = tid >> 6;              // 0..7
    int lane = tid & 63;
    int wm   = wv >> 2, wnn = wv & 3; // 2x4 wave grid, wave tile 128(M) x 64(N)
    int lrow = lane & 15, lquad = lane >> 4;
    int rl8  = lane >> 3, c8 = lane & 7;     // staging: 8 rows x 8 uint4 per wave-call
    int csw  = c8 ^ (rl8 & 7);               // store-side swizzled global uint4 col
    int swz  = lrow & 7;                     // read-side swizzle key

    // tiled zb: A tile for K-step t is contiguous [256 tok][64 ch] at (b8+t)*1024 + tokbase
    int b8      = (mtile >> 2) * 8;          // image * 8 ch-groups
    int tokbase = (mtile & 3) * 256;         // token offset within image
    const uint4* Ag = (const uint4*)zb;                              // rows of 8 uint4
    const uint4* Bg = (const uint4*)(eb + (size_t)ntile * 256 * D);  // row stride 64 uint4

    floatx4 acc[8][4];
#pragma unroll
    for (int f = 0; f < 8; ++f)
#pragma unroll
        for (int g = 0; g < 4; ++g) acc[f][g] = (floatx4){0.f, 0.f, 0.f, 0.f};

#define STAGE(sl, t) do {                                                                  \
        _Pragma("unroll")                                                                  \
        for (int q = 0; q < 4; ++q) {                                                      \
            int rb = wv * 32 + q * 8;      /* wave-uniform row base */                     \
            GLD_LDS16(Ag + ((size_t)(b8 + (t)) * 1024 + tokbase + rb + rl8) * 8 + csw,     \
                      &As[sl][rb * 64]);                                                   \
            GLD_LDS16(Bg + (size_t)(rb + rl8) * 64 + (t) * 8 + csw, &Bs[sl][rb * 64]);     \
        }                                                                                  \
    } while (0)

#define STEP(sl) do {                                                                      \
        _Pragma("unroll")                                                                  \
        for (int kh = 0; kh < 2; ++kh) {                                                   \
            short8 bf[4], af[8];                                                           \
            const int cL = ((kh * 4 + lquad) ^ swz) << 3;                                  \
            _Pragma("unroll")                                                              \
            for (int g = 0; g < 4; ++g)                                                    \
                bf[g] = *(const short8*)&Bs[sl][(wnn * 64 + g * 16 + lrow) * 64 + cL];     \
            _Pragma("unroll")                                                              \
            for (int f = 0; f < 8; ++f)                                                    \
                af[f] = *(const short8*)&As[sl][(wm * 128 + f * 16 + lrow) * 64 + cL];     \
            _Pragma("unroll")                                                              \
            for (int f = 0; f < 8; ++f)                                                    \
                _Pragma("unroll")                                                          \
                for (int g = 0; g < 4; ++g)                                                \
                    acc[f][g] = __builtin_amdgcn_mfma_f32_16x16x32_bf16(af[f], bf[g],      \
                                                                        acc[f][g], 0, 0, 0);\
        }                                                                                  \
    } while (0)

    STAGE(0, 0);
    __syncthreads();

#pragma unroll
    for (int t = 0; t < 8; ++t) {
        if (t < 7) STAGE((t + 1) & 1, t + 1);
        STEP(t & 1);
        __syncthreads();
    }
#undef STAGE
#undef STEP

    float es[4];
#pragma unroll
    for (int g = 0; g < 4; ++g) es[g] = esq[ntile * 256 + wnn * 64 + g * 16 + lrow];

    unsigned int* scr = (unsigned int*)&As[0][0];
#pragma unroll
    for (int f = 0; f < 8; ++f) {
#pragma unroll
        for (int r = 0; r < 4; ++r) {
            unsigned int best = 0xFFFFFFFFu;
#pragma unroll
            for (int g = 0; g < 4; ++g) {
                float dist = es[g] - 2.0f * acc[f][g][r];
                unsigned int kidx = (unsigned int)(ntile * 256 + wnn * 64 + g * 16 + lrow);
                unsigned int p = (fkey(dist) & 0xFFFFF800u) | kidx;
                best = p < best ? p : best;
            }
#pragma unroll
            for (int o = 1; o < 16; o <<= 1) {
                unsigned int other = (unsigned int)__shfl_xor((int)best, o);
                best = other < best ? other : best;
            }
            if (lrow == 0)
                scr[wnn * 256 + wm * 128 + f * 16 + lquad * 4 + r] = best;
        }
    }
    __syncthreads();
    if (tid < 256) {
        unsigned int b0 = scr[tid];
        unsigned int b1 = scr[256 + tid];
        unsigned int b2 = scr[512 + tid];
        unsigned int b3 = scr[768 + tid];
        b0 = b1 < b0 ? b1 : b0;
        b2 = b3 < b2 ? b3 : b2;
        b0 = b2 < b0 ? b2 : b0;
        atomicMin(&minb[mtile * 256 + tid], b0);
    }
}

// ---------------- Kernel O5: gather + NCHW write + loss, contiguous panels (pz fold: 512) ----------------
__global__ __launch_bounds__(256) void ko3(const float* __restrict__ emb,
                                           const unsigned int* __restrict__ minb,
                                           const float* __restrict__ pz,
                                           float* __restrict__ out,
                                           float* __restrict__ parts,
                                           unsigned int* __restrict__ cnt2) {
    __shared__ int   idx[1024];
    __shared__ float qt[8][1024];
    __shared__ float red[4];
    __shared__ int finflag;
    int blk = blockIdx.x;            // 0..1023
    int b   = blk >> 6;              // image 0..15
    int cg  = blk & 63;              // channel group 0..63 (8 channels each)
    int c0  = cg * 8;
    int tid = threadIdx.x;

    if (tid == 0) finflag = 0;

    float lv = 0.f;
#pragma unroll
    for (int i = 0; i < 4; ++i) {
        int t = tid + 256 * i;
        unsigned int key = minb[b * 1024 + t];
        idx[t] = (int)(key & 0x7FFu);
        if (cg == 0) lv += unfkey(key & 0xFFFFF800u);
    }
    __syncthreads();

    if (cg == 0) {
#pragma unroll
        for (int o = 32; o; o >>= 1) lv += __shfl_down(lv, o);
        if ((tid & 63) == 0) red[tid >> 6] = lv;
        __syncthreads();
        if (tid == 0) {
            parts[b] = red[0] + red[1] + red[2] + red[3];
            __threadfence();
            finflag = (atomicAdd(cnt2, 1u) == 15u);
        }
    }

    int half = tid & 1;
    int tb   = tid >> 1;
#pragma unroll
    for (int i = 0; i < 8; ++i) {
        int t = tb + 128 * i;
        float4 v = *(const float4*)(emb + (size_t)idx[t] * D + c0 + half * 4);
        qt[half * 4 + 0][t] = v.x; qt[half * 4 + 1][t] = v.y;
        qt[half * 4 + 2][t] = v.z; qt[half * 4 + 3][t] = v.w;
    }
    __syncthreads();

    float4* ob = (float4*)(out + ((size_t)b * D + c0) * HW);
    const float4* qb = (const float4*)&qt[0][0];
#pragma unroll
    for (int i = 0; i < 8; ++i)
        ob[tid + 256 * i] = qb[tid + 256 * i];

    __syncthreads();
    if (finflag) {
        float sv = (tid < 16) ? atomicAdd(&parts[tid], 0.0f) : 0.f;
        sv += pz[tid] + pz[256 + tid];           // fold 512 z^2 partials
#pragma unroll
        for (int o = 32; o; o >>= 1) sv += __shfl_down(sv, o);
        if ((tid & 63) == 0) red[tid >> 6] = sv;
        __syncthreads();
        if (tid == 0)
            out[NUMEL] = 1.25f * (red[0] + red[1] + red[2] + red[3]) / 8388608.0f;
    }
}

extern "C" void kernel_launch(void* const* d_in, const int* in_sizes, int n_in,
                              void* d_out, int out_size, void* d_ws, size_t ws_size,
                              hipStream_t stream) {
    const float* z   = (const float*)d_in[0];   // [16,512,32,32]
    const float* emb = (const float*)d_in[1];   // [2048,512]
    char* ws = (char*)d_ws;
    __hip_bfloat16* zb   = (__hip_bfloat16*)(ws + WS_ZB);
    __hip_bfloat16* eb   = (__hip_bfloat16*)(ws + WS_EB);
    float*          esq  = (float*)(ws + WS_ESQ);
    unsigned int*   minb = (unsigned int*)(ws + WS_MINB);
    float*          pz   = (float*)(ws + WS_PZ);
    float*          parts= (float*)(ws + WS_PARTS);
    unsigned int*   cnt2 = (unsigned int*)(ws + WS_CNT2);
    float* out = (float*)d_out;

    kp <<< 768, 256, 0, stream>>>(z, emb, zb, eb, esq, pz, minb, cnt2);
    kg <<< 512, 512, 0, stream>>>(zb, eb, esq, minb);
    ko3<<<1024, 256, 0, stream>>>(emb, minb, pz, out, parts, cnt2);
}